// Round 13
// baseline (303.011 us; speedup 1.0000x reference)
//
#include <hip/hip_runtime.h>

// DepthDeformConvPack on MI355X — round 17: resubmit r16 (infra failure, no
// signal). r15 post-mortem stands: fused = 121.4 = K3+K2 exactly (fusion
// neutral), so k_prep_offset ~= 138us — WITHOUT atomics. The offset conv has
// been the hidden ~120-138us co-dominant kernel all along.
// Cause: per channel each wave reads 18 co x 9 weights at strided
// off_w[co*2880 + c*9 + t] -> 18 small scalar-load groups with an lgkmcnt
// wait each; ~720 serialized 150-300cy waits/wave through a thrashing sL1,
// 2 waves/SIMD can't hide it -> ~130us for ~12us of FMA.
// Fix: k_prep_w transposes off_w -> off_wT[c][co][t] (648B contiguous per
// channel -> batched s_load_dwordx8/16, ONE wait, prefetchable) and
// mask_w -> mwT[c][co][k] (same pathology in fused phase M). k_prep_offset
// and phase M change ONLY weight indexing; everything else = r15.
// Decisive readout: prep_offset 138 -> 20-35us predicted; if still >60 the
// theory is wrong and next step is MFMA-izing the offset conv.

typedef __bf16 bf16x8 __attribute__((ext_vector_type(8)));
typedef float f32x4 __attribute__((ext_vector_type(4)));
typedef float float2_u __attribute__((ext_vector_type(2), aligned(4)));

__device__ __forceinline__ unsigned short f2bf(float f) {
  unsigned b = __float_as_uint(f);
  return (unsigned short)((b + 0x7fffu + ((b >> 16) & 1u)) >> 16);
}

// ---------------------------------------------------------------------------
// P0: weight preps. grid 2304 x 256.
//   wbf[i]    = bf16(weight[i])                       (589824)
//   off_wT[c*162 + co*9 + t] = off_w[co*2880 + c*9+t] (51840, channel-major)
//   mwT[c*81 + co*9 + k]     = mask_w[co*576 + c*9+k] (5184,  channel-major)
// ---------------------------------------------------------------------------
__global__ __launch_bounds__(256) void k_prep_w(
    const float* __restrict__ w, const float* __restrict__ off_w,
    const float* __restrict__ mask_w,
    unsigned short* __restrict__ wbf, float* __restrict__ off_wT,
    float* __restrict__ mwT)
{
  const int i = blockIdx.x * 256 + threadIdx.x;   // 0..589823
  wbf[i] = f2bf(w[i]);
  if (i < 51840) {
    const unsigned c = (unsigned)i / 162u, r = (unsigned)i - c * 162u;
    const unsigned co = r / 9u, t = r - co * 9u;
    off_wT[i] = off_w[co * 2880 + c * 9 + t];
  }
  if (i < 5184) {
    const unsigned c = (unsigned)i / 81u, r = (unsigned)i - c * 81u;
    const unsigned co = r / 9u, t = r - co * 9u;
    mwT[i] = mask_w[co * 576 + c * 9 + t];
  }
}

// ---------------------------------------------------------------------------
// P1: offset conv, full 320-ch reduction per block (no atomics, no memset).
// 256 blocks x 512 thr; block = (n,ho); 8 waves x 40 channels each.
// Weights read channel-major from off_wT (contiguous 648B per channel).
// ---------------------------------------------------------------------------
__global__ __launch_bounds__(512) void k_prep_offset(
    const float* __restrict__ x, const float* __restrict__ depth,
    const float* __restrict__ off_wT, const float* __restrict__ off_b,
    float* __restrict__ offs)
{
  const int tid = threadIdx.x;
  const int n = blockIdx.x >> 6, ho = blockIdx.x & 63;
  const int lane = tid & 63;              // == wo
  const int wave = tid >> 6;              // 0..7

  float acc[18];
#pragma unroll
  for (int i = 0; i < 18; ++i) acc[i] = 0.f;

  const int c0 = __builtin_amdgcn_readfirstlane(wave * 40);

  for (int ci = 0; ci < 40; ++ci) {
    const int c = c0 + ci;
    const float* p = (c < 256) ? (x + (((n << 8) + c) << 12))
                               : (depth + (((n << 6) + (c - 256)) << 12));
    const float v0 = (ho > 0)  ? p[((ho - 1) << 6) + lane] : 0.f;
    const float v1 =             p[( ho      << 6) + lane];
    const float v2 = (ho < 63) ? p[((ho + 1) << 6) + lane] : 0.f;

    float v[9];
#pragma unroll
    for (int ky = 0; ky < 3; ++ky) {
      const float r = (ky == 0) ? v0 : ((ky == 1) ? v1 : v2);
#pragma unroll
      for (int kx = 0; kx < 3; ++kx) {
        const int src = lane + kx - 1;
        const float s = __shfl(r, src & 63);
        v[ky * 3 + kx] = (src >= 0 && src < 64) ? s : 0.f;
      }
    }
    const float* wp = off_wT + c * 162;   // wave-uniform, CONTIGUOUS 648B
#pragma unroll
    for (int co = 0; co < 18; ++co) {
#pragma unroll
      for (int t = 0; t < 9; ++t) acc[co] += v[t] * wp[co * 9 + t];
    }
  }

  __shared__ float red[8][18][64];       // 36864 B
#pragma unroll
  for (int co = 0; co < 18; ++co) red[wave][co][lane] = acc[co];
  __syncthreads();
  for (int o = tid; o < 18 * 64; o += 512) {
    const int co = o >> 6, wo = o & 63;
    float s = off_b[co];
#pragma unroll
    for (int wv = 0; wv < 8; ++wv) s += red[wv][co][wo];
    offs[((n * 18 + co) << 12) + (ho << 6) + wo] = s;   // direct store
  }
}

// ---------------------------------------------------------------------------
// P2: fused mask deform conv + main modulated deform conv GEMM.  (= r15 with
// mwT channel-major mask weights.)
// LDS pool layout (101376 B):
//   [0      .. 78336) strip   9 x 8704
//   [78336  .. 87552) Bs      64 x 72 u16     \
//   [87552  .. 96768) pwT     9 x 64 float4    > aliased by red[8][9][64]
//   [96768  .. 99072) piT     9 x 64 int      /  (18432 B, phase-M only)
//   [99072  ..101376) mskL    9 x 64 float
// ---------------------------------------------------------------------------
__device__ __forceinline__ void stage_channel_row(const float* src, char* dstb,
                                                  int lane) {
  // 32 rows x 256B; each size-4 call writes one row (64 lanes x 4B, linear).
  const char* s = (const char*)src + lane * 4;
#pragma unroll
  for (int j = 0; j < 32; ++j)
    __builtin_amdgcn_global_load_lds(
        (const __attribute__((address_space(1))) void*)(s + j * 256),
        (__attribute__((address_space(3))) void*)(dstb + j * 272), 4, 0, 0);
}

__global__ __launch_bounds__(512, 2) void k_fused_gemm(
    const float* __restrict__ x, const float* __restrict__ depth,
    const float* __restrict__ offs, const float* __restrict__ mwT,
    const float* __restrict__ mask_b, const unsigned short* __restrict__ wbf,
    const float* __restrict__ bias, float* __restrict__ out)
{
  __shared__ __align__(16) char pool[101376];
  char* stripc = pool;
  unsigned short (*Bs)[72]  = (unsigned short (*)[72])(pool + 78336);
  float4 (*pwT)[64]         = (float4 (*)[64])(pool + 87552);
  int (*piT)[64]            = (int (*)[64])(pool + 96768);
  float (*mskL)[64]         = (float (*)[64])(pool + 99072);
  float (*red)[9][64]       = (float (*)[9][64])(pool + 78336);  // phase-M alias

  const int tid = threadIdx.x;
  // XCD swizzle: b&7 = XCD; each XCD owns a 32-row strip of one batch.
  const int b    = blockIdx.x;            // 256 blocks
  const int xcd  = b & 7, bslot = b >> 3; // bslot 0..31
  const int n    = xcd >> 1;
  const int ho   = ((xcd & 1) << 5) + bslot;      // 0..63
  const int pxb  = ho << 6;                       // px base within batch
  const int ylo  = min(max(ho - 15, 0), 32);      // strip rows [ylo, ylo+32)

  const int pxl  = tid & 63;        // px within row (= lane)
  const int oct  = tid >> 6;        // wave id; k-octet of 8
  const int lane = tid & 63;
  const int mrow = lane & 15;
  const int koct = lane >> 4;       // 0..3 -> k-subgroup of 8
  const float* xn = x + ((long)(n << 8) << 12);

  // --- prologue: stage channels 0..7 (window of iter 0), one per wave.
  // In flight during the whole mask phase; drained at the first barrier.
  stage_channel_row(xn + (oct << 12) + (ylo << 6), stripc + oct * 8704, lane);
  int c_staged = 8;

  // =============== Phase M: mask deform conv for this (n,ho) row ===========
  {
    const int wo = lane;
    int ia[9], ib[9];
    float w0[9], w1[9], w2c[9], w3[9];
    const float* op = offs + ((n * 18) << 12) + (ho << 6) + wo;
#pragma unroll
    for (int k = 0; k < 9; ++k) {
      const float dy = op[(2 * k) << 12];
      const float dx = op[(2 * k + 1) << 12];
      const float yy = (float)(ho - 1 + k / 3) + dy;
      const float xx = (float)(wo - 1 + k % 3) + dx;
      const float y0f = floorf(yy), x0f = floorf(xx);
      const float ly = yy - y0f, lx = xx - x0f;
      const int y0 = (int)y0f, x0 = (int)x0f;
      const int y0c = min(max(y0, 0), 63);
      const int y1c = min(max(y0 + 1, 0), 63);
      const float fy0 = (y0 >= 0 && y0 < 64) ? 1.f : 0.f;
      const float fy1 = (y0 >= -1 && y0 < 63) ? 1.f : 0.f;
      const int x0c = min(max(x0, 0), 63);
      const int x1c = min(max(x0 + 1, 0), 63);
      const int bx  = min(max(x0, 0), 62);
      const float vx0 = (x0 >= 0 && x0 < 64) ? 1.f : 0.f;
      const float vx1 = (x0 >= -1 && x0 < 63) ? 1.f : 0.f;
      const float wl = (1.f - lx) * vx0 * ((x0c == bx) ? 1.f : 0.f)
                     + lx * vx1 * ((x1c == bx) ? 1.f : 0.f);
      const float wr = (1.f - lx) * vx0 * ((x0c == bx + 1) ? 1.f : 0.f)
                     + lx * vx1 * ((x1c == bx + 1) ? 1.f : 0.f);
      const float a0 = (1.f - ly) * fy0;
      const float a1 = ly * fy1;
      ia[k] = ((y0c << 6) + bx) << 2;
      ib[k] = ((y1c << 6) + bx) << 2;
      w0[k] = wl * a0;  w1[k] = wr * a0;
      w2c[k] = wl * a1; w3[k] = wr * a1;
    }

    float acc2[9];
#pragma unroll
    for (int i = 0; i < 9; ++i) acc2[i] = 0.f;

    const int cbase = __builtin_amdgcn_readfirstlane(oct * 8);
    for (int cc = 0; cc < 8; ++cc) {
      const int c = cbase + cc;
      const char* p = (const char*)(depth + (((n << 6) + c) << 12));
      float val[9];
#pragma unroll
      for (int k = 0; k < 9; ++k) {
        const float2_u A = *(const float2_u*)(p + ia[k]);
        const float2_u B = *(const float2_u*)(p + ib[k]);
        val[k] = A.x * w0[k] + A.y * w1[k] + B.x * w2c[k] + B.y * w3[k];
      }
      const float* wp = mwT + c * 81;    // wave-uniform, CONTIGUOUS 324B
#pragma unroll
      for (int co = 0; co < 9; ++co) {
#pragma unroll
        for (int k = 0; k < 9; ++k) acc2[co] += val[k] * wp[co * 9 + k];
      }
    }
#pragma unroll
    for (int co = 0; co < 9; ++co) red[oct][co][lane] = acc2[co];
  }
  __syncthreads();   // red complete (also drains prologue staging vmcnt)

  for (int o = tid; o < 576; o += 512) {
    const int co = o >> 6, wo = o & 63;
    float s = mask_b[co];
#pragma unroll
    for (int wv = 0; wv < 8; ++wv) s += red[wv][co][wo];
    mskL[co][wo] = 1.f / (1.f + expf(-s));
  }
  __syncthreads();   // mskL ready; red dead -> Bs/pwT/piT region free

  // =============== Phase P: sampling params into LDS tables ================
  for (int e = tid; e < 576; e += 512) {
    const int tap = e >> 6, pl = e & 63;
    const int wo = pl;
    const float dy = offs[((n * 18 + 2 * tap) << 12) + pxb + pl];
    const float dx = offs[((n * 18 + 2 * tap + 1) << 12) + pxb + pl];
    const float m  = mskL[tap][pl];
    const float yy = (float)(ho - 1 + tap / 3) + dy;
    const float xx = (float)(wo - 1 + tap % 3) + dx;
    const float y0f = floorf(yy), x0f = floorf(xx);
    const float ly = yy - y0f, lx = xx - x0f;
    const int y0 = (int)y0f, x0 = (int)x0f;
    const int y0c = min(max(y0, 0), 63);
    const int y1c = min(max(y0 + 1, 0), 63);
    const float fy0 = (y0 >= 0 && y0 < 64) ? 1.f : 0.f;
    const float fy1 = (y0 >= -1 && y0 < 63) ? 1.f : 0.f;
    const int x0c = min(max(x0, 0), 63);
    const int x1c = min(max(x0 + 1, 0), 63);
    const int bx  = min(max(x0, 0), 62);
    const float vx0 = (x0 >= 0 && x0 < 64) ? 1.f : 0.f;
    const float vx1 = (x0 >= -1 && x0 < 63) ? 1.f : 0.f;
    const float wl = (1.f - lx) * vx0 * ((x0c == bx) ? 1.f : 0.f)
                   + lx * vx1 * ((x1c == bx) ? 1.f : 0.f);
    const float wr = (1.f - lx) * vx0 * ((x0c == bx + 1) ? 1.f : 0.f)
                   + lx * vx1 * ((x1c == bx + 1) ? 1.f : 0.f);
    const float a0 = (1.f - ly) * fy0 * m;
    const float a1 = ly * fy1 * m;
    pwT[tap][pl] = make_float4(wl * a0, wr * a0, wl * a1, wr * a1);
    // strip-relative byte addrs (row stride 272B) + bad flag
    const int ry0 = y0c - ylo, ry1 = y1c - ylo;
    const int ry0c = min(max(ry0, 0), 31), ry1c = min(max(ry1, 0), 31);
    const int bad = ((ry0 != ry0c) || (ry1 != ry1c)) ? 1 : 0;
    const int ad0 = ry0c * 272 + (bx << 2);      // <= 8680 < 16384
    const int ad1 = ry1c * 272 + (bx << 2);
    piT[tap][pl] = ad0 | (ad1 << 14) | (bad << 28);
  }
  __syncthreads();   // params + prologue strip visible

  // --- gather: one k-octet (8 k) per lane into Bs; params from LDS tables.
  auto gather = [&](int ic) {
    const int k0 = (ic << 6) + (oct << 3);
    const int c0 = (int)(((unsigned)k0 * 7282u) >> 16);    // k0/9
    int tap = k0 - 9 * c0;
    const int s9 = (int)(((unsigned)c0 * 7282u) >> 16);    // c0/9
    int soff = (c0 - 9 * s9) * 8704;                       // slot byte offset

    __align__(16) unsigned short v[8];
    unsigned badm = 0;
#pragma unroll
    for (int j = 0; j < 8; ++j) {
      const int pk  = piT[tap][pxl];              // ds_read_b32
      const float4 w = pwT[tap][pxl];             // ds_read_b128
      const float2_u A = *(const float2_u*)(stripc + soff + (pk & 16383));
      const float2_u B = *(const float2_u*)(stripc + soff + ((pk >> 14) & 16383));
      v[j] = f2bf(A.x * w.x + A.y * w.y + B.x * w.z + B.y * w.w);
      badm |= ((unsigned)pk >> 28) << j;          // bit28 = bad
      if (++tap == 9) {
        tap = 0;
        soff += 8704; if (soff == 9 * 8704) soff = 0;
      }
    }

    if (__builtin_expect(badm != 0, 0)) {         // ~10 events per launch
#pragma unroll
      for (int j = 0; j < 8; ++j) if (badm & (1u << j)) {
        const int k = k0 + j;
        const int c = (int)(((unsigned)k * 7282u) >> 16);
        const int tp = k - 9 * c;
        // full recompute from global (identical math to phase P)
        const float dy = offs[((n * 18 + 2 * tp) << 12) + pxb + pxl];
        const float dx = offs[((n * 18 + 2 * tp + 1) << 12) + pxb + pxl];
        const float m  = mskL[tp][pxl];
        const float yy = (float)(ho - 1 + tp / 3) + dy;
        const float xx = (float)(pxl - 1 + tp % 3) + dx;
        const float y0f = floorf(yy), x0f = floorf(xx);
        const float ly = yy - y0f, lx = xx - x0f;
        const int y0 = (int)y0f, x0 = (int)x0f;
        const int y0c = min(max(y0, 0), 63);
        const int y1c = min(max(y0 + 1, 0), 63);
        const float fy0 = (y0 >= 0 && y0 < 64) ? 1.f : 0.f;
        const float fy1 = (y0 >= -1 && y0 < 63) ? 1.f : 0.f;
        const int x0c = min(max(x0, 0), 63);
        const int x1c = min(max(x0 + 1, 0), 63);
        const int bx  = min(max(x0, 0), 62);
        const float vx0 = (x0 >= 0 && x0 < 64) ? 1.f : 0.f;
        const float vx1 = (x0 >= -1 && x0 < 63) ? 1.f : 0.f;
        const float wl = (1.f - lx) * vx0 * ((x0c == bx) ? 1.f : 0.f)
                       + lx * vx1 * ((x1c == bx) ? 1.f : 0.f);
        const float wr = (1.f - lx) * vx0 * ((x0c == bx + 1) ? 1.f : 0.f)
                       + lx * vx1 * ((x1c == bx + 1) ? 1.f : 0.f);
        const float a0 = (1.f - ly) * fy0 * m;
        const float a1 = ly * fy1 * m;
        const char* pg = (const char*)xn + ((long)c << 14);
        const float2_u Ag = *(const float2_u*)(pg + (((y0c << 6) + bx) << 2));
        const float2_u Bg = *(const float2_u*)(pg + (((y1c << 6) + bx) << 2));
        v[j] = f2bf(Ag.x * (wl * a0) + Ag.y * (wr * a0) +
                    Bg.x * (wl * a1) + Bg.y * (wr * a1));
      }
    }
    *(int4*)&Bs[pxl][oct << 3] = *(const int4*)v;
  };

  // A-fragment prefetch registers for iter 0
  bf16x8 afc[2][2];
#pragma unroll
  for (int mt = 0; mt < 2; ++mt)
#pragma unroll
    for (int ks = 0; ks < 2; ++ks) {
      const int row = (oct << 5) + (mt << 4) + mrow;
      const int col = (ks << 5) + (koct << 3);
      afc[mt][ks] = *(const bf16x8*)(wbf + row * 2304 + col);
    }

  gather(0);
  __syncthreads();

  f32x4 acc[2][4];
#pragma unroll
  for (int mt = 0; mt < 2; ++mt)
#pragma unroll
    for (int nt = 0; nt < 4; ++nt)
#pragma unroll
      for (int r = 0; r < 4; ++r) acc[mt][nt][r] = 0.f;

  for (int ic = 0; ic < 36; ++ic) {
    // stage next window (overlaps MFMA; drained at barrier) + af prefetch
    if (ic < 35) {
      const int c_end = (64 * ic + 127) / 9;          // c_hi(ic+1) <= 255
      const int cw = c_staged + oct;
      if (cw <= c_end) {
        const int slt = cw - 9 * (int)(((unsigned)cw * 7282u) >> 16);
        stage_channel_row(xn + (cw << 12) + (ylo << 6),
                          stripc + slt * 8704, lane);
      }
      c_staged = c_end + 1;
    }

    bf16x8 afn[2][2];
    if (ic < 35) {
      const int kc = (ic + 1) << 6;
#pragma unroll
      for (int mt = 0; mt < 2; ++mt)
#pragma unroll
        for (int ks = 0; ks < 2; ++ks) {
          const int row = (oct << 5) + (mt << 4) + mrow;
          const int col = kc + (ks << 5) + (koct << 3);
          afn[mt][ks] = *(const bf16x8*)(wbf + row * 2304 + col);
        }
    }

#pragma unroll
    for (int ks = 0; ks < 2; ++ks)
#pragma unroll
      for (int nt = 0; nt < 4; ++nt) {
        const bf16x8 bfr =
            *(const bf16x8*)&Bs[(nt << 4) + mrow][(ks << 5) + (koct << 3)];
        acc[0][nt] = __builtin_amdgcn_mfma_f32_16x16x32_bf16(afc[0][ks], bfr,
                                                             acc[0][nt], 0, 0, 0);
        acc[1][nt] = __builtin_amdgcn_mfma_f32_16x16x32_bf16(afc[1][ks], bfr,
                                                             acc[1][nt], 0, 0, 0);
      }

    __syncthreads();           // drains stage; Bs free for rewrite
    if (ic < 35) gather(ic + 1);
    __syncthreads();           // Bs ready for next MFMA; strip safe to restage

#pragma unroll
    for (int mt = 0; mt < 2; ++mt)
#pragma unroll
      for (int ks = 0; ks < 2; ++ks) afc[mt][ks] = afn[mt][ks];
  }

  // epilogue: C/D layout col=lane&15 (px), row=(lane>>4)*4+r (co)
#pragma unroll
  for (int mt = 0; mt < 2; ++mt)
#pragma unroll
    for (int nt = 0; nt < 4; ++nt)
#pragma unroll
      for (int r = 0; r < 4; ++r) {
        const int co = (oct << 5) + (mt << 4) + ((lane >> 4) << 2) + r;
        const int pxg = pxb + (nt << 4) + (lane & 15);
        out[(((n << 8) + co) << 12) + pxg] = acc[mt][nt][r] + bias[co];
      }
}

// ---------------------------------------------------------------------------
extern "C" void kernel_launch(void* const* d_in, const int* in_sizes, int n_in,
                              void* d_out, int out_size, void* d_ws, size_t ws_size,
                              hipStream_t stream) {
  const float* x      = (const float*)d_in[0];
  const float* depth  = (const float*)d_in[1];
  const float* weight = (const float*)d_in[2];
  const float* bias   = (const float*)d_in[3];
  const float* off_w  = (const float*)d_in[4];
  const float* off_b  = (const float*)d_in[5];
  const float* mask_w = (const float*)d_in[6];
  const float* mask_b = (const float*)d_in[7];
  float* out = (float*)d_out;

  float* offs = (float*)d_ws;                              // 294912 f
  unsigned short* wbf = (unsigned short*)(offs + 294912);  // 589824 u16
  float* off_wT = (float*)(wbf + 589824);                  // 51840 f
  float* mwT    = off_wT + 51840;                          // 5184 f

  k_prep_w<<<2304, 256, 0, stream>>>(weight, off_w, mask_w, wbf, off_wT, mwT);
  k_prep_offset<<<256, 512, 0, stream>>>(x, depth, off_wT, off_b, offs);
  k_fused_gemm<<<256, 512, 0, stream>>>(x, depth, offs, mwT, mask_b,
                                        wbf, bias, out);
}

// Round 14
// 239.887 us; speedup vs baseline: 1.2631x; 1.2631x over previous
//
#include <hip/hip_runtime.h>

// DepthDeformConvPack on MI355X — round 18: revert to r14 (243.7us best) +
// 8-waves/SIMD K1. r17 post-mortem: weight transpose REFUTED (total 303,
// fused unchanged 122); accounting corrected — prep_offset never appears in
// top-5 so it is <=122us, and the "138us" was kernel+launch-gap conflation.
// Ladder truth: r13/r14 (5 dispatches) = 243.7-245.2 best; r15's K1 merge
// (2 waves/SIMD) was SLOWER than r13's K1 (4 waves/SIMD) -> K1 is
// latency-bound on its load->shfl->fma chain (VALU floor ~22us vs ~100
// measured). Fix: K1 at 512 thr = 8 waves x 10 ch, same 1024-block grid ->
// 32 waves/CU = 8/SIMD (hw max). red[8][18][64]=36.9KB x 4 blocks/CU fits.
// Atomics unchanged (1.18M). K0/K2/K3 byte-identical to r14.
// Decisive: K1 ~100 -> ~55-70 predicted, total -> ~195-215; if unchanged,
// latency theory also dead -> next is replacing ds_bpermute shuffles.

typedef __bf16 bf16x8 __attribute__((ext_vector_type(8)));
typedef float f32x4 __attribute__((ext_vector_type(4)));
typedef float float2_u __attribute__((ext_vector_type(2), aligned(4)));

__device__ __forceinline__ unsigned short f2bf(float f) {
  unsigned b = __float_as_uint(f);
  return (unsigned short)((b + 0x7fffu + ((b >> 16) & 1u)) >> 16);
}

// ---------------------------------------------------------------------------
// K0: weight fp32 -> bf16, natural layout (k = c*9+tap is already channel-major)
// ---------------------------------------------------------------------------
__global__ __launch_bounds__(256) void k_prep_weight(
    const float* __restrict__ w, unsigned short* __restrict__ wbf)
{
  const int i = blockIdx.x * 256 + threadIdx.x;   // grid 2304 -> 589824
  wbf[i] = f2bf(w[i]);
}

// ---------------------------------------------------------------------------
// K1: offset conv. grid = 4 ch-segments x (n,ho)=256 -> 1024 blocks, 512 thr.
// 8 waves x 10 channels each -> 32 waves/CU (8/SIMD, hw max) for latency
// hiding on the load->shfl->fma chain.
// ---------------------------------------------------------------------------
__global__ __launch_bounds__(512) void k_offset_conv(
    const float* __restrict__ x, const float* __restrict__ depth,
    const float* __restrict__ off_w, const float* __restrict__ off_b,
    float* __restrict__ offs)
{
  const int seg = blockIdx.x >> 8;        // 0..3
  const int nh  = blockIdx.x & 255;
  const int n = nh >> 6, ho = nh & 63;
  const int tid = threadIdx.x;
  const int lane = tid & 63;              // == wo
  const int wave = tid >> 6;              // 0..7

  float acc[18];
#pragma unroll
  for (int i = 0; i < 18; ++i) acc[i] = 0.f;

  const int c0 = __builtin_amdgcn_readfirstlane(seg * 80 + wave * 10);

  for (int ci = 0; ci < 10; ++ci) {
    const int c = c0 + ci;
    const float* p = (c < 256) ? (x + (((n << 8) + c) << 12))
                               : (depth + (((n << 6) + (c - 256)) << 12));
    const float v0 = (ho > 0)  ? p[((ho - 1) << 6) + lane] : 0.f;
    const float v1 =             p[( ho      << 6) + lane];
    const float v2 = (ho < 63) ? p[((ho + 1) << 6) + lane] : 0.f;

    float v[9];
#pragma unroll
    for (int ky = 0; ky < 3; ++ky) {
      const float r = (ky == 0) ? v0 : ((ky == 1) ? v1 : v2);
#pragma unroll
      for (int kx = 0; kx < 3; ++kx) {
        const int src = lane + kx - 1;
        const float s = __shfl(r, src & 63);
        v[ky * 3 + kx] = (src >= 0 && src < 64) ? s : 0.f;
      }
    }
    const float* wp = off_w + c * 9;   // wave-uniform address
#pragma unroll
    for (int co = 0; co < 18; ++co) {
      const float* w = wp + co * 2880;
#pragma unroll
      for (int t = 0; t < 9; ++t) acc[co] += v[t] * w[t];
    }
  }

  __shared__ float red[8][18][64];        // 36864 B
#pragma unroll
  for (int co = 0; co < 18; ++co) red[wave][co][lane] = acc[co];
  __syncthreads();
  for (int o = tid; o < 18 * 64; o += 512) {
    const int co = o >> 6, wo = o & 63;
    float s = 0.f;
#pragma unroll
    for (int wv = 0; wv < 8; ++wv) s += red[wv][co][wo];
    if (seg == 0) s += off_b[co];
    atomicAdd(&offs[((n * 18 + co) << 12) + (ho << 6) + wo], s);
  }
}

// ---------------------------------------------------------------------------
// K2: mask deform conv on depth + sigmoid. 256 blocks (n,ho), 512 thr = 8 waves.
// Pair-load gather: per tap, 2x float2_u row-pair loads with folded weights.
// ---------------------------------------------------------------------------
__global__ __launch_bounds__(512) void k_mask_conv(
    const float* __restrict__ depth, const float* __restrict__ offs,
    const float* __restrict__ mask_w, const float* __restrict__ mask_b,
    float* __restrict__ mask)
{
  const int n  = blockIdx.x >> 6;
  const int ho = blockIdx.x & 63;
  const int tid  = threadIdx.x;
  const int lane = tid & 63;          // wo
  const int wave = tid >> 6;          // 0..7
  const int wo = lane;

  int ia[9], ib[9];
  float w0[9], w1[9], w2c[9], w3[9];
  const float* op = offs + ((n * 18) << 12) + (ho << 6) + wo;
#pragma unroll
  for (int k = 0; k < 9; ++k) {
    const float dy = op[(2 * k) << 12];
    const float dx = op[(2 * k + 1) << 12];
    const float yy = (float)(ho - 1 + k / 3) + dy;
    const float xx = (float)(wo - 1 + k % 3) + dx;
    const float y0f = floorf(yy), x0f = floorf(xx);
    const float ly = yy - y0f, lx = xx - x0f;
    const int y0 = (int)y0f, x0 = (int)x0f;
    const int y0c = min(max(y0, 0), 63);
    const int y1c = min(max(y0 + 1, 0), 63);
    const float fy0 = (y0 >= 0 && y0 < 64) ? 1.f : 0.f;
    const float fy1 = (y0 >= -1 && y0 < 63) ? 1.f : 0.f;
    // horizontal pair remap (K3-proven): contribution = wl*p[bx] + wr*p[bx+1]
    const int x0c = min(max(x0, 0), 63);
    const int x1c = min(max(x0 + 1, 0), 63);
    const int bx  = min(max(x0, 0), 62);
    const float vx0 = (x0 >= 0 && x0 < 64) ? 1.f : 0.f;
    const float vx1 = (x0 >= -1 && x0 < 63) ? 1.f : 0.f;
    const float wl = (1.f - lx) * vx0 * ((x0c == bx) ? 1.f : 0.f)
                   + lx * vx1 * ((x1c == bx) ? 1.f : 0.f);
    const float wr = (1.f - lx) * vx0 * ((x0c == bx + 1) ? 1.f : 0.f)
                   + lx * vx1 * ((x1c == bx + 1) ? 1.f : 0.f);
    const float a0 = (1.f - ly) * fy0;
    const float a1 = ly * fy1;
    ia[k] = ((y0c << 6) + bx) << 2;     // byte offsets
    ib[k] = ((y1c << 6) + bx) << 2;
    w0[k] = wl * a0;  w1[k] = wr * a0;
    w2c[k] = wl * a1; w3[k] = wr * a1;
  }

  float acc[9];
#pragma unroll
  for (int i = 0; i < 9; ++i) acc[i] = 0.f;

  const int cbase = __builtin_amdgcn_readfirstlane(wave * 8);
  for (int cc = 0; cc < 8; ++cc) {
    const int c = cbase + cc;
    const char* p = (const char*)(depth + (((n << 6) + c) << 12));
    float val[9];
#pragma unroll
    for (int k = 0; k < 9; ++k) {
      const float2_u A = *(const float2_u*)(p + ia[k]);
      const float2_u B = *(const float2_u*)(p + ib[k]);
      val[k] = A.x * w0[k] + A.y * w1[k] + B.x * w2c[k] + B.y * w3[k];
    }
    const float* wp = mask_w + c * 9;
#pragma unroll
    for (int co = 0; co < 9; ++co) {
#pragma unroll
      for (int k = 0; k < 9; ++k) acc[co] += val[k] * wp[co * 576 + k];
    }
  }

  __shared__ float red[8][9][64];
#pragma unroll
  for (int co = 0; co < 9; ++co) red[wave][co][lane] = acc[co];
  __syncthreads();
  for (int o = tid; o < 9 * 64; o += 512) {
    const int co = o >> 6, w2 = o & 63;
    float s = mask_b[co];
#pragma unroll
    for (int w = 0; w < 8; ++w) s += red[w][co][w2];
    mask[((n * 9 + co) << 12) + (ho << 6) + w2] = 1.f / (1.f + expf(-s));
  }
}

// ---------------------------------------------------------------------------
// K3: main modulated deform conv, bf16 MFMA GEMM, channel-major K.  (= r14)
// C[256co x 16384px] = Wbf[256 x 2304] * cols[2304 x px], k = c*9 + tap.
// Block: BN=64 px (one output row), BM=256, BK=64, 512 thr = 8 waves, grid 256.
// x staged via 32x size-4 global_load_lds calls per channel (one 256B row
// each) at 272B LDS stride. Params in LDS tables with precomputed offsets.
// ---------------------------------------------------------------------------
__device__ __forceinline__ void stage_channel_row(const float* src, char* dstb,
                                                  int lane) {
  // 32 rows x 256B; each size-4 call writes one row (64 lanes x 4B, linear).
  const char* s = (const char*)src + lane * 4;
#pragma unroll
  for (int j = 0; j < 32; ++j)
    __builtin_amdgcn_global_load_lds(
        (const __attribute__((address_space(1))) void*)(s + j * 256),
        (__attribute__((address_space(3))) void*)(dstb + j * 272), 4, 0, 0);
}

__global__ __launch_bounds__(512, 2) void k_deform_gemm(
    const float* __restrict__ x, const float* __restrict__ offs,
    const float* __restrict__ mask, const unsigned short* __restrict__ wbf,
    const float* __restrict__ bias, float* __restrict__ out)
{
  __shared__ float strip[9 * 2176];                    // 9 x 8704 B = 78336 B
  __shared__ __align__(16) unsigned short Bs[64][72];  // 9216 B
  __shared__ float4 pwT[9][64];                        // 9216 B
  __shared__ int    piT[9][64];                        // 2304 B -> 99072 B

  const int tid = threadIdx.x;
  // XCD swizzle: b&7 = XCD; each XCD owns a 32-row strip of one batch.
  const int b    = blockIdx.x;            // 256 blocks
  const int xcd  = b & 7, bslot = b >> 3; // bslot 0..31
  const int n    = xcd >> 1;
  const int ho   = ((xcd & 1) << 5) + bslot;      // 0..63
  const int pxb  = ho << 6;                       // px base within batch
  const int ylo  = min(max(ho - 15, 0), 32);      // strip rows [ylo, ylo+32)

  const int pxl  = tid & 63;        // px within row (= lane)
  const int oct  = tid >> 6;        // wave id; k-octet of 8
  const int lane = tid & 63;
  const int mrow = lane & 15;
  const int koct = lane >> 4;       // 0..3 -> k-subgroup of 8
  const float* xn = x + ((long)(n << 8) << 12);
  const char* xnc = (const char*)xn;
  char* stripc = (char*)strip;

  // --- prologue: stage channels 0..7 (window of iter 0), one per wave
  stage_channel_row(xn + (oct << 12) + (ylo << 6), stripc + oct * 8704, lane);
  int c_staged = 8;

  // --- phase 0: sampling params into LDS tables (e = tap*64 + px)
  for (int e = tid; e < 576; e += 512) {
    const int tap = e >> 6, pl = e & 63;
    const int wo = pl;
    const float dy = offs[((n * 18 + 2 * tap) << 12) + pxb + pl];
    const float dx = offs[((n * 18 + 2 * tap + 1) << 12) + pxb + pl];
    const float m  = mask[((n * 9 + tap) << 12) + pxb + pl];
    const float yy = (float)(ho - 1 + tap / 3) + dy;
    const float xx = (float)(wo - 1 + tap % 3) + dx;
    const float y0f = floorf(yy), x0f = floorf(xx);
    const float ly = yy - y0f, lx = xx - x0f;
    const int y0 = (int)y0f, x0 = (int)x0f;
    const int y0c = min(max(y0, 0), 63);
    const int y1c = min(max(y0 + 1, 0), 63);
    const float fy0 = (y0 >= 0 && y0 < 64) ? 1.f : 0.f;
    const float fy1 = (y0 >= -1 && y0 < 63) ? 1.f : 0.f;
    // horizontal pair remap: contribution = wl*p[bx] + wr*p[bx+1]
    const int x0c = min(max(x0, 0), 63);
    const int x1c = min(max(x0 + 1, 0), 63);
    const int bx  = min(max(x0, 0), 62);
    const float vx0 = (x0 >= 0 && x0 < 64) ? 1.f : 0.f;
    const float vx1 = (x0 >= -1 && x0 < 63) ? 1.f : 0.f;
    const float wl = (1.f - lx) * vx0 * ((x0c == bx) ? 1.f : 0.f)
                   + lx * vx1 * ((x1c == bx) ? 1.f : 0.f);
    const float wr = (1.f - lx) * vx0 * ((x0c == bx + 1) ? 1.f : 0.f)
                   + lx * vx1 * ((x1c == bx + 1) ? 1.f : 0.f);
    const float a0 = (1.f - ly) * fy0 * m;
    const float a1 = ly * fy1 * m;
    pwT[tap][pl] = make_float4(wl * a0, wr * a0, wl * a1, wr * a1);
    // strip-relative byte addrs in the row-rotated layout + bad flag:
    // ad = ry*272 + bx*4  (max 8680 < 16384)
    const int ry0 = y0c - ylo, ry1 = y1c - ylo;
    const int ry0c = min(max(ry0, 0), 31), ry1c = min(max(ry1, 0), 31);
    const int bad = ((ry0 != ry0c) || (ry1 != ry1c)) ? 1 : 0;
    const int ad0 = ry0c * 272 + (bx << 2);
    const int ad1 = ry1c * 272 + (bx << 2);
    piT[tap][pl] = ad0 | (ad1 << 14) | (bad << 28);
  }
  __syncthreads();   // params + prologue strip visible (barrier drains vmcnt)

  // --- gather: one k-octet (8 k) per lane into Bs; params from LDS tables.
  auto gather = [&](int ic) {
    const int k0 = (ic << 6) + (oct << 3);
    const int c0 = (int)(((unsigned)k0 * 7282u) >> 16);    // k0/9
    int tap = k0 - 9 * c0;
    const int s9 = (int)(((unsigned)c0 * 7282u) >> 16);    // c0/9
    int soff = (c0 - 9 * s9) * 8704;                       // slot byte offset

    __align__(16) unsigned short v[8];
    unsigned badm = 0;
#pragma unroll
    for (int j = 0; j < 8; ++j) {
      const int pk  = piT[tap][pxl];              // ds_read_b32
      const float4 w = pwT[tap][pxl];             // ds_read_b128
      const float2_u A = *(const float2_u*)(stripc + soff + (pk & 16383));
      const float2_u B = *(const float2_u*)(stripc + soff + ((pk >> 14) & 16383));
      v[j] = f2bf(A.x * w.x + A.y * w.y + B.x * w.z + B.y * w.w);
      badm |= ((unsigned)pk >> 28) << j;          // bit28 = bad; bits 29-31 = 0
      if (++tap == 9) {
        tap = 0;
        soff += 8704; if (soff == 9 * 8704) soff = 0;
      }
    }

    if (__builtin_expect(badm != 0, 0)) {         // ~10 events per launch
#pragma unroll
      for (int j = 0; j < 8; ++j) if (badm & (1u << j)) {
        const int k = k0 + j;
        const int c = (int)(((unsigned)k * 7282u) >> 16);
        const int tp = k - 9 * c;
        // full recompute from global (identical math to phase 0)
        const float dy = offs[((n * 18 + 2 * tp) << 12) + pxb + pxl];
        const float dx = offs[((n * 18 + 2 * tp + 1) << 12) + pxb + pxl];
        const float m  = mask[((n * 9 + tp) << 12) + pxb + pxl];
        const float yy = (float)(ho - 1 + tp / 3) + dy;
        const float xx = (float)(pxl - 1 + tp % 3) + dx;
        const float y0f = floorf(yy), x0f = floorf(xx);
        const float ly = yy - y0f, lx = xx - x0f;
        const int y0 = (int)y0f, x0 = (int)x0f;
        const int y0c = min(max(y0, 0), 63);
        const int y1c = min(max(y0 + 1, 0), 63);
        const float fy0 = (y0 >= 0 && y0 < 64) ? 1.f : 0.f;
        const float fy1 = (y0 >= -1 && y0 < 63) ? 1.f : 0.f;
        const int x0c = min(max(x0, 0), 63);
        const int x1c = min(max(x0 + 1, 0), 63);
        const int bx  = min(max(x0, 0), 62);
        const float vx0 = (x0 >= 0 && x0 < 64) ? 1.f : 0.f;
        const float vx1 = (x0 >= -1 && x0 < 63) ? 1.f : 0.f;
        const float wl = (1.f - lx) * vx0 * ((x0c == bx) ? 1.f : 0.f)
                       + lx * vx1 * ((x1c == bx) ? 1.f : 0.f);
        const float wr = (1.f - lx) * vx0 * ((x0c == bx + 1) ? 1.f : 0.f)
                       + lx * vx1 * ((x1c == bx + 1) ? 1.f : 0.f);
        const float a0 = (1.f - ly) * fy0 * m;
        const float a1 = ly * fy1 * m;
        const char* pg = xnc + ((long)c << 14);
        const float2_u Ag = *(const float2_u*)(pg + (((y0c << 6) + bx) << 2));
        const float2_u Bg = *(const float2_u*)(pg + (((y1c << 6) + bx) << 2));
        v[j] = f2bf(Ag.x * (wl * a0) + Ag.y * (wr * a0) +
                    Bg.x * (wl * a1) + Bg.y * (wr * a1));
      }
    }
    *(int4*)&Bs[pxl][oct << 3] = *(const int4*)v;
  };

  // A-fragment prefetch registers for iter 0
  bf16x8 afc[2][2];
#pragma unroll
  for (int mt = 0; mt < 2; ++mt)
#pragma unroll
    for (int ks = 0; ks < 2; ++ks) {
      const int row = (oct << 5) + (mt << 4) + mrow;
      const int col = (ks << 5) + (koct << 3);
      afc[mt][ks] = *(const bf16x8*)(wbf + row * 2304 + col);
    }

  gather(0);
  __syncthreads();

  f32x4 acc[2][4];
#pragma unroll
  for (int mt = 0; mt < 2; ++mt)
#pragma unroll
    for (int nt = 0; nt < 4; ++nt)
#pragma unroll
      for (int r = 0; r < 4; ++r) acc[mt][nt][r] = 0.f;

  for (int ic = 0; ic < 36; ++ic) {
    // phase 1: stage next window (global_load_lds, overlaps MFMA; drained at
    // the barrier) + prefetch af(ic+1), MFMA(ic), barrier, gather(ic+1), barrier.
    if (ic < 35) {
      const int c_end = (64 * ic + 127) / 9;          // c_hi(ic+1) <= 255
      const int cw = c_staged + oct;
      if (cw <= c_end) {
        const int slt = cw - 9 * (int)(((unsigned)cw * 7282u) >> 16);
        stage_channel_row(xn + (cw << 12) + (ylo << 6),
                          stripc + slt * 8704, lane);
      }
      c_staged = c_end + 1;
    }

    bf16x8 afn[2][2];
    if (ic < 35) {
      const int kc = (ic + 1) << 6;
#pragma unroll
      for (int mt = 0; mt < 2; ++mt)
#pragma unroll
        for (int ks = 0; ks < 2; ++ks) {
          const int row = (oct << 5) + (mt << 4) + mrow;
          const int col = kc + (ks << 5) + (koct << 3);
          afn[mt][ks] = *(const bf16x8*)(wbf + row * 2304 + col);
        }
    }

#pragma unroll
    for (int ks = 0; ks < 2; ++ks)
#pragma unroll
      for (int nt = 0; nt < 4; ++nt) {
        const bf16x8 bfr =
            *(const bf16x8*)&Bs[(nt << 4) + mrow][(ks << 5) + (koct << 3)];
        acc[0][nt] = __builtin_amdgcn_mfma_f32_16x16x32_bf16(afc[0][ks], bfr,
                                                             acc[0][nt], 0, 0, 0);
        acc[1][nt] = __builtin_amdgcn_mfma_f32_16x16x32_bf16(afc[1][ks], bfr,
                                                             acc[1][nt], 0, 0, 0);
      }

    __syncthreads();           // drains stage; Bs free for rewrite
    if (ic < 35) gather(ic + 1);
    __syncthreads();           // Bs ready for next MFMA; strip safe to restage

#pragma unroll
    for (int mt = 0; mt < 2; ++mt)
#pragma unroll
      for (int ks = 0; ks < 2; ++ks) afc[mt][ks] = afn[mt][ks];
  }

  // epilogue: C/D layout col=lane&15 (px), row=(lane>>4)*4+r (co)
#pragma unroll
  for (int mt = 0; mt < 2; ++mt)
#pragma unroll
    for (int nt = 0; nt < 4; ++nt)
#pragma unroll
      for (int r = 0; r < 4; ++r) {
        const int co = (oct << 5) + (mt << 4) + ((lane >> 4) << 2) + r;
        const int pxg = pxb + (nt << 4) + (lane & 15);
        out[(((n << 8) + co) << 12) + pxg] = acc[mt][nt][r] + bias[co];
      }
}

// ---------------------------------------------------------------------------
extern "C" void kernel_launch(void* const* d_in, const int* in_sizes, int n_in,
                              void* d_out, int out_size, void* d_ws, size_t ws_size,
                              hipStream_t stream) {
  const float* x      = (const float*)d_in[0];
  const float* depth  = (const float*)d_in[1];
  const float* weight = (const float*)d_in[2];
  const float* bias   = (const float*)d_in[3];
  const float* off_w  = (const float*)d_in[4];
  const float* off_b  = (const float*)d_in[5];
  const float* mask_w = (const float*)d_in[6];
  const float* mask_b = (const float*)d_in[7];
  float* out = (float*)d_out;

  float* offs = (float*)d_ws;                       // 294912 floats
  float* mask = offs + 294912;                      // 147456 floats
  unsigned short* wbf = (unsigned short*)(mask + 147456);  // 589824 bf16

  hipMemsetAsync(offs, 0, 294912 * sizeof(float), stream);
  k_prep_weight<<<2304, 256, 0, stream>>>(weight, wbf);
  k_offset_conv<<<1024, 512, 0, stream>>>(x, depth, off_w, off_b, offs);
  k_mask_conv<<<256, 512, 0, stream>>>(depth, offs, mask_w, mask_b, mask);
  k_deform_gemm<<<256, 512, 0, stream>>>(x, offs, mask, wbf, bias, out);
}

// Round 15
// 235.647 us; speedup vs baseline: 1.2859x; 1.0180x over previous
//
#include <hip/hip_runtime.h>

// DepthDeformConvPack on MI355X — round 19: 2 dispatches, occupancy intact.
// r18 post-mortem (239.9 best): K1 4->8 waves/SIMD bought only 4us -> K1 is
// a 25-40us kernel, not ~100. Ledger: K3 102 + K1 ~30 + K2 ~22 + K0 3 +
// memset 2 = ~160 of 240 -> ~75us is per-dispatch fixed overhead (~15-20 x
// 4-5 boundaries). r15/r17's fusions couldn't see this: they also dropped
// K1 to 2 waves/SIMD (256blk x 8 waves) and the regression ate the savings.
// r19: two dispatches, each at proven-best occupancy:
//   D1 k_offset_all: 256 blk x 1024 thr (16 waves x 20ch = 4 waves/SIMD,
//      r13-K1's proven config) = K0 grid-stride prologue + full-320ch offset
//      conv + LDS reduce -> direct store. No memset, no atomics.
//   D2 k_fused_gemm: byte-identical to r15's fused K2+K3 (passed, 121.4us).
// Workspace 2.36MB (offs+wbf only; mask buffer gone).
// Decisive: total ~200 => gaps confirmed & near floor; total ~240 => gap
// theory dead, next round MFMA-izes the offset conv.

typedef __bf16 bf16x8 __attribute__((ext_vector_type(8)));
typedef float f32x4 __attribute__((ext_vector_type(4)));
typedef float float2_u __attribute__((ext_vector_type(2), aligned(4)));

__device__ __forceinline__ unsigned short f2bf(float f) {
  unsigned b = __float_as_uint(f);
  return (unsigned short)((b + 0x7fffu + ((b >> 16) & 1u)) >> 16);
}

// ---------------------------------------------------------------------------
// D1: weight prep (K0) + offset conv (K1, full-channel, no atomics).
// 256 blocks x 1024 thr; block = (n,ho); 16 waves x 20 channels each.
// ---------------------------------------------------------------------------
__global__ __launch_bounds__(1024) void k_offset_all(
    const float* __restrict__ x, const float* __restrict__ depth,
    const float* __restrict__ w, const float* __restrict__ off_w,
    const float* __restrict__ off_b,
    unsigned short* __restrict__ wbf, float* __restrict__ offs)
{
  const int tid = threadIdx.x;
  // --- K0: weight fp32 -> bf16, grid-stride (589824 / 262144 thr)
  for (int i = blockIdx.x * 1024 + tid; i < 589824; i += 262144)
    wbf[i] = f2bf(w[i]);

  const int n = blockIdx.x >> 6, ho = blockIdx.x & 63;
  const int lane = tid & 63;              // == wo
  const int wave = tid >> 6;              // 0..15

  float acc[18];
#pragma unroll
  for (int i = 0; i < 18; ++i) acc[i] = 0.f;

  const int c0 = __builtin_amdgcn_readfirstlane(wave * 20);

  for (int ci = 0; ci < 20; ++ci) {
    const int c = c0 + ci;
    const float* p = (c < 256) ? (x + (((n << 8) + c) << 12))
                               : (depth + (((n << 6) + (c - 256)) << 12));
    const float v0 = (ho > 0)  ? p[((ho - 1) << 6) + lane] : 0.f;
    const float v1 =             p[( ho      << 6) + lane];
    const float v2 = (ho < 63) ? p[((ho + 1) << 6) + lane] : 0.f;

    float v[9];
#pragma unroll
    for (int ky = 0; ky < 3; ++ky) {
      const float r = (ky == 0) ? v0 : ((ky == 1) ? v1 : v2);
#pragma unroll
      for (int kx = 0; kx < 3; ++kx) {
        const int src = lane + kx - 1;
        const float s = __shfl(r, src & 63);
        v[ky * 3 + kx] = (src >= 0 && src < 64) ? s : 0.f;
      }
    }
    const float* wp = off_w + c * 9;   // wave-uniform address
#pragma unroll
    for (int co = 0; co < 18; ++co) {
      const float* ww = wp + co * 2880;
#pragma unroll
      for (int t = 0; t < 9; ++t) acc[co] += v[t] * ww[t];
    }
  }

  __shared__ float red[16][18][64];       // 73728 B
#pragma unroll
  for (int co = 0; co < 18; ++co) red[wave][co][lane] = acc[co];
  __syncthreads();
  for (int o = tid; o < 18 * 64; o += 1024) {
    const int co = o >> 6, wo = o & 63;
    float s = off_b[co];
#pragma unroll
    for (int wv = 0; wv < 16; ++wv) s += red[wv][co][wo];
    offs[((n * 18 + co) << 12) + (ho << 6) + wo] = s;   // direct store
  }
}

// ---------------------------------------------------------------------------
// D2: fused mask deform conv (K2) + main modulated deform conv GEMM (K3).
// Block = (n,ho) via XCD swizzle, 512 thr = 8 waves, grid 256.  (= r15, passed)
// LDS pool layout (101376 B):
//   [0      .. 78336) strip   9 x 8704
//   [78336  .. 87552) Bs      64 x 72 u16     \
//   [87552  .. 96768) pwT     9 x 64 float4    > aliased by red[8][9][64]
//   [96768  .. 99072) piT     9 x 64 int      /  (18432 B, phase-M only)
//   [99072  ..101376) mskL    9 x 64 float
// ---------------------------------------------------------------------------
__device__ __forceinline__ void stage_channel_row(const float* src, char* dstb,
                                                  int lane) {
  // 32 rows x 256B; each size-4 call writes one row (64 lanes x 4B, linear).
  const char* s = (const char*)src + lane * 4;
#pragma unroll
  for (int j = 0; j < 32; ++j)
    __builtin_amdgcn_global_load_lds(
        (const __attribute__((address_space(1))) void*)(s + j * 256),
        (__attribute__((address_space(3))) void*)(dstb + j * 272), 4, 0, 0);
}

__global__ __launch_bounds__(512, 2) void k_fused_gemm(
    const float* __restrict__ x, const float* __restrict__ depth,
    const float* __restrict__ offs, const float* __restrict__ mask_w,
    const float* __restrict__ mask_b, const unsigned short* __restrict__ wbf,
    const float* __restrict__ bias, float* __restrict__ out)
{
  __shared__ __align__(16) char pool[101376];
  char* stripc = pool;
  unsigned short (*Bs)[72]  = (unsigned short (*)[72])(pool + 78336);
  float4 (*pwT)[64]         = (float4 (*)[64])(pool + 87552);
  int (*piT)[64]            = (int (*)[64])(pool + 96768);
  float (*mskL)[64]         = (float (*)[64])(pool + 99072);
  float (*red)[9][64]       = (float (*)[9][64])(pool + 78336);  // phase-M alias

  const int tid = threadIdx.x;
  // XCD swizzle: b&7 = XCD; each XCD owns a 32-row strip of one batch.
  const int b    = blockIdx.x;            // 256 blocks
  const int xcd  = b & 7, bslot = b >> 3; // bslot 0..31
  const int n    = xcd >> 1;
  const int ho   = ((xcd & 1) << 5) + bslot;      // 0..63
  const int pxb  = ho << 6;                       // px base within batch
  const int ylo  = min(max(ho - 15, 0), 32);      // strip rows [ylo, ylo+32)

  const int pxl  = tid & 63;        // px within row (= lane)
  const int oct  = tid >> 6;        // wave id; k-octet of 8
  const int lane = tid & 63;
  const int mrow = lane & 15;
  const int koct = lane >> 4;       // 0..3 -> k-subgroup of 8
  const float* xn = x + ((long)(n << 8) << 12);

  // --- prologue: stage channels 0..7 (window of iter 0), one per wave.
  // In flight during the whole mask phase; drained at the first barrier.
  stage_channel_row(xn + (oct << 12) + (ylo << 6), stripc + oct * 8704, lane);
  int c_staged = 8;

  // =============== Phase M: mask deform conv for this (n,ho) row ===========
  {
    const int wo = lane;
    int ia[9], ib[9];
    float w0[9], w1[9], w2c[9], w3[9];
    const float* op = offs + ((n * 18) << 12) + (ho << 6) + wo;
#pragma unroll
    for (int k = 0; k < 9; ++k) {
      const float dy = op[(2 * k) << 12];
      const float dx = op[(2 * k + 1) << 12];
      const float yy = (float)(ho - 1 + k / 3) + dy;
      const float xx = (float)(wo - 1 + k % 3) + dx;
      const float y0f = floorf(yy), x0f = floorf(xx);
      const float ly = yy - y0f, lx = xx - x0f;
      const int y0 = (int)y0f, x0 = (int)x0f;
      const int y0c = min(max(y0, 0), 63);
      const int y1c = min(max(y0 + 1, 0), 63);
      const float fy0 = (y0 >= 0 && y0 < 64) ? 1.f : 0.f;
      const float fy1 = (y0 >= -1 && y0 < 63) ? 1.f : 0.f;
      const int x0c = min(max(x0, 0), 63);
      const int x1c = min(max(x0 + 1, 0), 63);
      const int bx  = min(max(x0, 0), 62);
      const float vx0 = (x0 >= 0 && x0 < 64) ? 1.f : 0.f;
      const float vx1 = (x0 >= -1 && x0 < 63) ? 1.f : 0.f;
      const float wl = (1.f - lx) * vx0 * ((x0c == bx) ? 1.f : 0.f)
                     + lx * vx1 * ((x1c == bx) ? 1.f : 0.f);
      const float wr = (1.f - lx) * vx0 * ((x0c == bx + 1) ? 1.f : 0.f)
                     + lx * vx1 * ((x1c == bx + 1) ? 1.f : 0.f);
      const float a0 = (1.f - ly) * fy0;
      const float a1 = ly * fy1;
      ia[k] = ((y0c << 6) + bx) << 2;
      ib[k] = ((y1c << 6) + bx) << 2;
      w0[k] = wl * a0;  w1[k] = wr * a0;
      w2c[k] = wl * a1; w3[k] = wr * a1;
    }

    float acc2[9];
#pragma unroll
    for (int i = 0; i < 9; ++i) acc2[i] = 0.f;

    const int cbase = __builtin_amdgcn_readfirstlane(oct * 8);
    for (int cc = 0; cc < 8; ++cc) {
      const int c = cbase + cc;
      const char* p = (const char*)(depth + (((n << 6) + c) << 12));
      float val[9];
#pragma unroll
      for (int k = 0; k < 9; ++k) {
        const float2_u A = *(const float2_u*)(p + ia[k]);
        const float2_u B = *(const float2_u*)(p + ib[k]);
        val[k] = A.x * w0[k] + A.y * w1[k] + B.x * w2c[k] + B.y * w3[k];
      }
      const float* wp = mask_w + c * 9;
#pragma unroll
      for (int co = 0; co < 9; ++co) {
#pragma unroll
        for (int k = 0; k < 9; ++k) acc2[co] += val[k] * wp[co * 576 + k];
      }
    }
#pragma unroll
    for (int co = 0; co < 9; ++co) red[oct][co][lane] = acc2[co];
  }
  __syncthreads();   // red complete (also drains prologue staging vmcnt)

  for (int o = tid; o < 576; o += 512) {
    const int co = o >> 6, wo = o & 63;
    float s = mask_b[co];
#pragma unroll
    for (int wv = 0; wv < 8; ++wv) s += red[wv][co][wo];
    mskL[co][wo] = 1.f / (1.f + expf(-s));
  }
  __syncthreads();   // mskL ready; red dead -> Bs/pwT/piT region free

  // =============== Phase P: sampling params into LDS tables ================
  for (int e = tid; e < 576; e += 512) {
    const int tap = e >> 6, pl = e & 63;
    const int wo = pl;
    const float dy = offs[((n * 18 + 2 * tap) << 12) + pxb + pl];
    const float dx = offs[((n * 18 + 2 * tap + 1) << 12) + pxb + pl];
    const float m  = mskL[tap][pl];
    const float yy = (float)(ho - 1 + tap / 3) + dy;
    const float xx = (float)(wo - 1 + tap % 3) + dx;
    const float y0f = floorf(yy), x0f = floorf(xx);
    const float ly = yy - y0f, lx = xx - x0f;
    const int y0 = (int)y0f, x0 = (int)x0f;
    const int y0c = min(max(y0, 0), 63);
    const int y1c = min(max(y0 + 1, 0), 63);
    const float fy0 = (y0 >= 0 && y0 < 64) ? 1.f : 0.f;
    const float fy1 = (y0 >= -1 && y0 < 63) ? 1.f : 0.f;
    const int x0c = min(max(x0, 0), 63);
    const int x1c = min(max(x0 + 1, 0), 63);
    const int bx  = min(max(x0, 0), 62);
    const float vx0 = (x0 >= 0 && x0 < 64) ? 1.f : 0.f;
    const float vx1 = (x0 >= -1 && x0 < 63) ? 1.f : 0.f;
    const float wl = (1.f - lx) * vx0 * ((x0c == bx) ? 1.f : 0.f)
                   + lx * vx1 * ((x1c == bx) ? 1.f : 0.f);
    const float wr = (1.f - lx) * vx0 * ((x0c == bx + 1) ? 1.f : 0.f)
                   + lx * vx1 * ((x1c == bx + 1) ? 1.f : 0.f);
    const float a0 = (1.f - ly) * fy0 * m;
    const float a1 = ly * fy1 * m;
    pwT[tap][pl] = make_float4(wl * a0, wr * a0, wl * a1, wr * a1);
    // strip-relative byte addrs (row stride 272B) + bad flag
    const int ry0 = y0c - ylo, ry1 = y1c - ylo;
    const int ry0c = min(max(ry0, 0), 31), ry1c = min(max(ry1, 0), 31);
    const int bad = ((ry0 != ry0c) || (ry1 != ry1c)) ? 1 : 0;
    const int ad0 = ry0c * 272 + (bx << 2);      // <= 8680 < 16384
    const int ad1 = ry1c * 272 + (bx << 2);
    piT[tap][pl] = ad0 | (ad1 << 14) | (bad << 28);
  }
  __syncthreads();   // params + prologue strip visible

  // --- gather: one k-octet (8 k) per lane into Bs; params from LDS tables.
  auto gather = [&](int ic) {
    const int k0 = (ic << 6) + (oct << 3);
    const int c0 = (int)(((unsigned)k0 * 7282u) >> 16);    // k0/9
    int tap = k0 - 9 * c0;
    const int s9 = (int)(((unsigned)c0 * 7282u) >> 16);    // c0/9
    int soff = (c0 - 9 * s9) * 8704;                       // slot byte offset

    __align__(16) unsigned short v[8];
    unsigned badm = 0;
#pragma unroll
    for (int j = 0; j < 8; ++j) {
      const int pk  = piT[tap][pxl];              // ds_read_b32
      const float4 w = pwT[tap][pxl];             // ds_read_b128
      const float2_u A = *(const float2_u*)(stripc + soff + (pk & 16383));
      const float2_u B = *(const float2_u*)(stripc + soff + ((pk >> 14) & 16383));
      v[j] = f2bf(A.x * w.x + A.y * w.y + B.x * w.z + B.y * w.w);
      badm |= ((unsigned)pk >> 28) << j;          // bit28 = bad
      if (++tap == 9) {
        tap = 0;
        soff += 8704; if (soff == 9 * 8704) soff = 0;
      }
    }

    if (__builtin_expect(badm != 0, 0)) {         // ~10 events per launch
#pragma unroll
      for (int j = 0; j < 8; ++j) if (badm & (1u << j)) {
        const int k = k0 + j;
        const int c = (int)(((unsigned)k * 7282u) >> 16);
        const int tp = k - 9 * c;
        // full recompute from global (identical math to phase P)
        const float dy = offs[((n * 18 + 2 * tp) << 12) + pxb + pxl];
        const float dx = offs[((n * 18 + 2 * tp + 1) << 12) + pxb + pxl];
        const float m  = mskL[tp][pxl];
        const float yy = (float)(ho - 1 + tp / 3) + dy;
        const float xx = (float)(pxl - 1 + tp % 3) + dx;
        const float y0f = floorf(yy), x0f = floorf(xx);
        const float ly = yy - y0f, lx = xx - x0f;
        const int y0 = (int)y0f, x0 = (int)x0f;
        const int y0c = min(max(y0, 0), 63);
        const int y1c = min(max(y0 + 1, 0), 63);
        const float fy0 = (y0 >= 0 && y0 < 64) ? 1.f : 0.f;
        const float fy1 = (y0 >= -1 && y0 < 63) ? 1.f : 0.f;
        const int x0c = min(max(x0, 0), 63);
        const int x1c = min(max(x0 + 1, 0), 63);
        const int bx  = min(max(x0, 0), 62);
        const float vx0 = (x0 >= 0 && x0 < 64) ? 1.f : 0.f;
        const float vx1 = (x0 >= -1 && x0 < 63) ? 1.f : 0.f;
        const float wl = (1.f - lx) * vx0 * ((x0c == bx) ? 1.f : 0.f)
                       + lx * vx1 * ((x1c == bx) ? 1.f : 0.f);
        const float wr = (1.f - lx) * vx0 * ((x0c == bx + 1) ? 1.f : 0.f)
                       + lx * vx1 * ((x1c == bx + 1) ? 1.f : 0.f);
        const float a0 = (1.f - ly) * fy0 * m;
        const float a1 = ly * fy1 * m;
        const char* pg = (const char*)xn + ((long)c << 14);
        const float2_u Ag = *(const float2_u*)(pg + (((y0c << 6) + bx) << 2));
        const float2_u Bg = *(const float2_u*)(pg + (((y1c << 6) + bx) << 2));
        v[j] = f2bf(Ag.x * (wl * a0) + Ag.y * (wr * a0) +
                    Bg.x * (wl * a1) + Bg.y * (wr * a1));
      }
    }
    *(int4*)&Bs[pxl][oct << 3] = *(const int4*)v;
  };

  // A-fragment prefetch registers for iter 0
  bf16x8 afc[2][2];
#pragma unroll
  for (int mt = 0; mt < 2; ++mt)
#pragma unroll
    for (int ks = 0; ks < 2; ++ks) {
      const int row = (oct << 5) + (mt << 4) + mrow;
      const int col = (ks << 5) + (koct << 3);
      afc[mt][ks] = *(const bf16x8*)(wbf + row * 2304 + col);
    }

  gather(0);
  __syncthreads();

  f32x4 acc[2][4];
#pragma unroll
  for (int mt = 0; mt < 2; ++mt)
#pragma unroll
    for (int nt = 0; nt < 4; ++nt)
#pragma unroll
      for (int r = 0; r < 4; ++r) acc[mt][nt][r] = 0.f;

  for (int ic = 0; ic < 36; ++ic) {
    // stage next window (overlaps MFMA; drained at barrier) + af prefetch
    if (ic < 35) {
      const int c_end = (64 * ic + 127) / 9;          // c_hi(ic+1) <= 255
      const int cw = c_staged + oct;
      if (cw <= c_end) {
        const int slt = cw - 9 * (int)(((unsigned)cw * 7282u) >> 16);
        stage_channel_row(xn + (cw << 12) + (ylo << 6),
                          stripc + slt * 8704, lane);
      }
      c_staged = c_end + 1;
    }

    bf16x8 afn[2][2];
    if (ic < 35) {
      const int kc = (ic + 1) << 6;
#pragma unroll
      for (int mt = 0; mt < 2; ++mt)
#pragma unroll
        for (int ks = 0; ks < 2; ++ks) {
          const int row = (oct << 5) + (mt << 4) + mrow;
          const int col = kc + (ks << 5) + (koct << 3);
          afn[mt][ks] = *(const bf16x8*)(wbf + row * 2304 + col);
        }
    }

#pragma unroll
    for (int ks = 0; ks < 2; ++ks)
#pragma unroll
      for (int nt = 0; nt < 4; ++nt) {
        const bf16x8 bfr =
            *(const bf16x8*)&Bs[(nt << 4) + mrow][(ks << 5) + (koct << 3)];
        acc[0][nt] = __builtin_amdgcn_mfma_f32_16x16x32_bf16(afc[0][ks], bfr,
                                                             acc[0][nt], 0, 0, 0);
        acc[1][nt] = __builtin_amdgcn_mfma_f32_16x16x32_bf16(afc[1][ks], bfr,
                                                             acc[1][nt], 0, 0, 0);
      }

    __syncthreads();           // drains stage; Bs free for rewrite
    if (ic < 35) gather(ic + 1);
    __syncthreads();           // Bs ready for next MFMA; strip safe to restage

#pragma unroll
    for (int mt = 0; mt < 2; ++mt)
#pragma unroll
      for (int ks = 0; ks < 2; ++ks) afc[mt][ks] = afn[mt][ks];
  }

  // epilogue: C/D layout col=lane&15 (px), row=(lane>>4)*4+r (co)
#pragma unroll
  for (int mt = 0; mt < 2; ++mt)
#pragma unroll
    for (int nt = 0; nt < 4; ++nt)
#pragma unroll
      for (int r = 0; r < 4; ++r) {
        const int co = (oct << 5) + (mt << 4) + ((lane >> 4) << 2) + r;
        const int pxg = pxb + (nt << 4) + (lane & 15);
        out[(((n << 8) + co) << 12) + pxg] = acc[mt][nt][r] + bias[co];
      }
}

// ---------------------------------------------------------------------------
extern "C" void kernel_launch(void* const* d_in, const int* in_sizes, int n_in,
                              void* d_out, int out_size, void* d_ws, size_t ws_size,
                              hipStream_t stream) {
  const float* x      = (const float*)d_in[0];
  const float* depth  = (const float*)d_in[1];
  const float* weight = (const float*)d_in[2];
  const float* bias   = (const float*)d_in[3];
  const float* off_w  = (const float*)d_in[4];
  const float* off_b  = (const float*)d_in[5];
  const float* mask_w = (const float*)d_in[6];
  const float* mask_b = (const float*)d_in[7];
  float* out = (float*)d_out;

  float* offs = (float*)d_ws;                              // 294912 f
  unsigned short* wbf = (unsigned short*)(offs + 294912);  // 589824 u16

  k_offset_all<<<256, 1024, 0, stream>>>(x, depth, weight, off_w, off_b,
                                         wbf, offs);
  k_fused_gemm<<<256, 512, 0, stream>>>(x, depth, offs, mask_w, mask_b,
                                        wbf, bias, out);
}